// Round 21
// baseline (150.114 us; speedup 1.0000x reference)
//
#include <hip/hip_runtime.h>
#include <hip/hip_bf16.h>

// Shapes (fixed): B=8, H=W=32, E=768, nh=12, hd=64, N=1024, BH=96
// ws layout (bytes):
//   xb      @ 0          : 12,582,912  (x cast to bf16)
//   wqkvT   @ 12582912   :  3,538,944  (Wqkv^T bf16, PI-column-ordered)
//   wprojT  @ 16121856   :  1,179,648  (Wproj^T bf16)
//   qkvb    @ 17301504   : 37,748,736  (Vrow bf16 [12.6MB], then attn-out bf16)
//   Q       @ 55050240   : 12,582,912
//   K       @ 67633152   : 12,582,912
//   Vt      @ 80216064   : 12,582,912  (V transposed: [bh][d][n])

typedef __attribute__((ext_vector_type(8))) short short8;
typedef __attribute__((ext_vector_type(4))) float f32x4;

__global__ __launch_bounds__(256) void cast_f32_bf16(const float* __restrict__ in,
                                                     __hip_bfloat16* __restrict__ out) {
  int i = (blockIdx.x * 256 + threadIdx.x) * 4;
  float4 v = *(const float4*)&in[i];
  out[i + 0] = __float2bfloat16(v.x);
  out[i + 1] = __float2bfloat16(v.y);
  out[i + 2] = __float2bfloat16(v.z);
  out[i + 3] = __float2bfloat16(v.w);
}

// in [K][N] f32 -> out [N][K] bf16  (plain; used for Wproj)
__global__ __launch_bounds__(256) void transpose_cast(const float* __restrict__ in,
                                                      __hip_bfloat16* __restrict__ out,
                                                      int K, int N) {
  __shared__ float tile[32][33];
  int n0 = blockIdx.x * 32, k0 = blockIdx.y * 32;
  int tx = threadIdx.x & 31, ty = threadIdx.x >> 5;  // 32 x 8
#pragma unroll
  for (int i = 0; i < 4; ++i)
    tile[ty + i * 8][tx] = in[(size_t)(k0 + ty + i * 8) * N + n0 + tx];
  __syncthreads();
#pragma unroll
  for (int i = 0; i < 4; ++i)
    out[(size_t)(n0 + ty + i * 8) * K + k0 + tx] = __float2bfloat16(tile[tx][ty + i * 8]);
}

// PI-ordered transpose for Wqkv (verified R18): column j = c2*768 + h*64 + d2
// (dest coords), source column pi(j) = h*192 + (u&63)*3 + (u>>6), u = 3*d2+c2.
__global__ __launch_bounds__(256) void transpose_cast_pi(const float* __restrict__ in,
                                                         __hip_bfloat16* __restrict__ out) {
  __shared__ float tile[32][33];
  int n0 = blockIdx.x * 32, k0 = blockIdx.y * 32;
  int tx = threadIdx.x & 31, ty = threadIdx.x >> 5;  // 32 x 8
  int j = n0 + tx;
  int c2 = j / 768, rem = j - c2 * 768;
  int h = rem >> 6, d2 = rem & 63;
  int u = 3 * d2 + c2;
  int src = h * 192 + (u & 63) * 3 + (u >> 6);   // pi(j)
#pragma unroll
  for (int i = 0; i < 4; ++i)
    tile[ty + i * 8][tx] = in[(size_t)(k0 + ty + i * 8) * 2304 + src];
  __syncthreads();
#pragma unroll
  for (int i = 0; i < 4; ++i)
    out[(size_t)(n0 + ty + i * 8) * 768 + k0 + tx] = __float2bfloat16(tile[tx][ty + i * 8]);
}

// Vrow [bh][n][d] -> Vt [bh][d][n], LDS-tiled 64x64.
__global__ __launch_bounds__(256) void vtrans(const __hip_bfloat16* __restrict__ Vrow,
                                              __hip_bfloat16* __restrict__ Vt) {
  int bh = blockIdx.y, n0 = blockIdx.x * 64;
  __shared__ short t[64][72];
  int tid = threadIdx.x;
  const short* src = (const short*)Vrow + (size_t)bh * 65536 + (size_t)n0 * 64;
#pragma unroll
  for (int i = 0; i < 2; ++i) {
    int c8 = tid + i * 256;          // 0..511 chunks of 8
    int nl = c8 >> 3, off = (c8 & 7) * 8;
    *(short8*)&t[nl][off] = *(const short8*)&src[nl * 64 + off];
  }
  __syncthreads();
  int d = tid >> 2, g4 = tid & 3;
  short8 v0, v1;
#pragma unroll
  for (int j = 0; j < 8; ++j) v0[j] = t[g4 * 16 + j][d];
#pragma unroll
  for (int j = 0; j < 8; ++j) v1[j] = t[g4 * 16 + 8 + j][d];
  size_t base = (size_t)bh * 65536 + (size_t)d * 1024 + n0 + g4 * 16;
  *(short8*)&Vt[base] = v0;
  *(short8*)&Vt[base + 8] = v1;
}

__device__ inline void gload16(const void* g, void* l) {
  __builtin_amdgcn_global_load_lds((const __attribute__((address_space(1))) void*)g,
                                   (__attribute__((address_space(3))) void*)l, 16, 0, 0);
}

// C = A[M,K]*Bt[N,K]^T + bias ; BMx128 tile, 4 waves (2x2), BK=64.
// Counted-vmcnt double-buffered pipeline + both-sides XOR swizzle (R16)
// + T5 s_setprio around the MFMA cluster (phase-split waves -> scheduler
// arbitration pays; guide m218b/m224).
// MODE 0: f32 C (gemm2).  MODE 1: PI-direct epilogue (gemm1), verified R19.
template<int BM, int MODE>
__global__ __launch_bounds__(256) void gemm_pipe(const __hip_bfloat16* __restrict__ A,
                                                 const __hip_bfloat16* __restrict__ Bt,
                                                 const float* __restrict__ bias,
                                                 float* __restrict__ Cf32,
                                                 __hip_bfloat16* __restrict__ Qd,
                                                 __hip_bfloat16* __restrict__ Kdd,
                                                 __hip_bfloat16* __restrict__ Vd,
                                                 int N, int K) {
  constexpr int FM = BM / 32;               // m-frags per wave (4 or 2)
  constexpr int ABYTES = BM * 128;          // bytes per A k-tile
  constexpr int AOPW = BM / 32;             // A DMA ops per wave per tile
  __shared__ __align__(16) char lds[2 * ABYTES + 2 * 16384];
  char* Abuf = lds;                         // [2][ABYTES]
  char* Bbuf = lds + 2 * ABYTES;            // [2][16384]
  int n0 = blockIdx.x * 128, m0 = blockIdx.y * BM;
  int tid = threadIdx.x, lane = tid & 63, wid = tid >> 6;
  int wm = wid >> 1, wn = wid & 1;
  int lr = lane & 15, lg = lane >> 4;
  int xr = lr & 7;
  int g_ = lane >> 3;                       // row-in-op (8 rows x 128B per op)
  int colsw = ((lane & 7) ^ g_) * 8;        // pre-swizzled source col (elements)
  f32x4 acc[FM][4] = {};

  // ---- prologue: stage k-tile 0 into buf 0 (AOPW+4 ops/wave, in flight) ----
#pragma unroll
  for (int j = 0; j < AOPW; ++j) {
    int op = wid * AOPW + j;
    gload16(&A[(size_t)(m0 + op * 8 + g_) * K + colsw], Abuf + op * 1024);
  }
#pragma unroll
  for (int j = 0; j < 4; ++j) {
    int op = wid * 4 + j;
    gload16(&Bt[(size_t)(n0 + op * 8 + g_) * K + colsw], Bbuf + op * 1024);
  }

  int cur = 0;
#pragma unroll 1
  for (int k0 = 0; k0 < K; k0 += 64) {
    __builtin_amdgcn_sched_barrier(0);
    __builtin_amdgcn_s_barrier();          // buf^1 reads (tile k-1) complete
    int kn = (k0 + 64 < K) ? k0 + 64 : k0; // last iter: dummy restage
#pragma unroll
    for (int j = 0; j < AOPW; ++j) {
      int op = wid * AOPW + j;
      gload16(&A[(size_t)(m0 + op * 8 + g_) * K + kn + colsw],
              Abuf + (cur ^ 1) * ABYTES + op * 1024);
    }
#pragma unroll
    for (int j = 0; j < 4; ++j) {
      int op = wid * 4 + j;
      gload16(&Bt[(size_t)(n0 + op * 8 + g_) * K + kn + colsw],
              Bbuf + (cur ^ 1) * 16384 + op * 1024);
    }
    // retire this wave's tile-k DMA (keep the AOPW+4 newest in flight)
    if constexpr (BM == 128) asm volatile("s_waitcnt vmcnt(8)" ::: "memory");
    else                     asm volatile("s_waitcnt vmcnt(6)" ::: "memory");
    __builtin_amdgcn_sched_barrier(0);
    __builtin_amdgcn_s_barrier();          // ALL waves' tile-k DMA retired
    __builtin_amdgcn_sched_barrier(0);

    const char* Ac = Abuf + cur * ABYTES;
    const char* Bc = Bbuf + cur * 16384;
#pragma unroll
    for (int ks = 0; ks < 2; ++ks) {
      short8 af[FM], bfr[4];
#pragma unroll
      for (int m = 0; m < FM; ++m) {
        int row = wm * (BM / 2) + m * 16 + lr;
        af[m] = *(const short8*)(Ac + row * 128 + (((ks * 4 + lg) ^ xr) * 16));
      }
#pragma unroll
      for (int n = 0; n < 4; ++n) {
        int row = wn * 64 + n * 16 + lr;
        bfr[n] = *(const short8*)(Bc + row * 128 + (((ks * 4 + lg) ^ xr) * 16));
      }
      __builtin_amdgcn_s_setprio(1);
#pragma unroll
      for (int m = 0; m < FM; ++m)
#pragma unroll
        for (int n = 0; n < 4; ++n)
          acc[m][n] = __builtin_amdgcn_mfma_f32_16x16x32_bf16(af[m], bfr[n], acc[m][n], 0, 0, 0);
      __builtin_amdgcn_s_setprio(0);
    }
    cur ^= 1;
  }
#pragma unroll
  for (int n = 0; n < 4; ++n) {
    int j = n0 + wn * 64 + n * 16 + lr;    // PI-ordered (dest-coord) column
    if constexpr (MODE == 0) {
      float bv = bias[j];
#pragma unroll
      for (int m = 0; m < FM; ++m) {
        int rowb = m0 + wm * (BM / 2) + m * 16 + lg * 4;
#pragma unroll
        for (int r = 0; r < 4; ++r)
          Cf32[(size_t)(rowb + r) * N + j] = acc[m][n][r] + bv;
      }
    } else {
      int c = j / 768, rem = j - c * 768;  // c uniform per frag, h per frag
      int h = rem >> 6, dd = rem & 63;     // dd lane-consecutive
      int u = 3 * dd + c;
      float bv = bias[h * 192 + (u & 63) * 3 + (u >> 6)];  // bias[pi(j)]
      __hip_bfloat16* dst = (c == 0) ? Qd : ((c == 1) ? Kdd : Vd);
#pragma unroll
      for (int m = 0; m < FM; ++m) {
        int rowb = m0 + wm * (BM / 2) + m * 16 + lg * 4;
#pragma unroll
        for (int r = 0; r < 4; ++r) {
          float v = acc[m][n][r] + bv;
          int W = (rowb + r) * 12 + h;
          int bh = W >> 10, n2 = W & 1023;
          dst[(size_t)bh * 65536 + n2 * 64 + dd] = __float2bfloat16(v);
        }
      }
    }
  }
}

__device__ inline short8 cvt8(const float* p) {
  short8 r;
#pragma unroll
  for (int j = 0; j < 8; ++j) {
    __hip_bfloat16 b = __float2bfloat16(p[j]);
    r[j] = *reinterpret_cast<const short*>(&b);
  }
  return r;
}

// truncation pack: [b_hi16 | a_hi16] in one v_perm_b32 (valid: P>=0, no NaN).
__device__ inline unsigned packtrunc(float a, float b) {
  return __builtin_amdgcn_perm(__float_as_uint(b), __float_as_uint(a), 0x07060302u);
}

// Flash attention v14 (= v13 + T5 setprio around QK^T and PV MFMA clusters):
// 8 waves/block (512 thr), 16 q-rows/wave, grid 768. Counted-vmcnt protocol;
// LDS 49152 B.
#define L2E 1.44269504088896f
__global__ __launch_bounds__(512) void attn14(const __hip_bfloat16* __restrict__ Q,
                                              const __hip_bfloat16* __restrict__ Kd,
                                              const __hip_bfloat16* __restrict__ Vt,
                                              const float* __restrict__ rph,
                                              const float* __restrict__ rpw,
                                              __hip_bfloat16* __restrict__ outp) {
  int orig = blockIdx.x;                   // 768 = 8 xcd * 96
  int xcd = orig & 7, loc = orig >> 3;     // 96 per xcd
  int bh = xcd * 12 + (loc % 12);
  int qt = loc / 12;                       // 0..7 (128-row q tile)
  int tid = threadIdx.x;
  int lane = tid & 63, w = tid >> 6;       // w in [0,8)
  int lr = lane & 15, lg = lane >> 4;
  int xr = lr & 7;

  __shared__ __align__(16) char lds[49152];

  const __hip_bfloat16* Qb = Q + (size_t)bh * 65536;
  const __hip_bfloat16* Kb = Kd + (size_t)bh * 65536;
  const __hip_bfloat16* Vb = Vt + (size_t)bh * 65536;

  int q0 = qt * 128 + w * 16;              // this wave's 16 q-rows
  int hq = q0 >> 5;                        // = qt*4 + (w>>1)
  int wq_lane = (q0 & 31) + lr;            // = (w&1)*16 + lr

  short8 qf0 = *(const short8*)&Qb[(size_t)(q0 + lr) * 64 + lg * 8];
  short8 qf1 = *(const short8*)&Qb[(size_t)(q0 + lr) * 64 + 32 + lg * 8];

  // ---- rel-pos bias via MFMA (pre-scaled by L2E); swizzled-slot store ----
  char* rhb = lds + 24576 + w * 1024;      // [16 q][64B], pair-slot swizzled
#pragma unroll
  for (int kt = 0; kt < 2; ++kt) {
    int row = hq - (kt * 16 + lr) + 31;    // 0..62
    const float* tp = rph + (size_t)row * 64 + lg * 8;
    short8 th0 = cvt8(tp), th1 = cvt8(tp + 32);
    f32x4 a = {};
    a = __builtin_amdgcn_mfma_f32_16x16x32_bf16(qf0, th0, a, 0, 0, 0);
    a = __builtin_amdgcn_mfma_f32_16x16x32_bf16(qf1, th1, a, 0, 0, 0);
#pragma unroll
    for (int r = 0; r < 4; ++r) {
      int q = lg * 4 + r;                  // 0..15
      int e = kt * 16 + lr;                // kh element 0..31
      int sw = ((e >> 1) ^ q) << 2;
      *(__hip_bfloat16*)(rhb + q * 64 + sw + (e & 1) * 2) = __float2bfloat16(a[r] * L2E);
    }
  }
  // rw staging in the (still dead) K/V region: wave w at byte w*2176, [16][68] bf16
  __hip_bfloat16* rwt = (__hip_bfloat16*)(lds + w * 2176);
#pragma unroll
  for (int jt = 0; jt < 4; ++jt) {
    const float* tp = rpw + (size_t)(jt * 16 + lr) * 64 + lg * 8;
    short8 tw0 = cvt8(tp), tw1 = cvt8(tp + 32);
    f32x4 a = {};
    a = __builtin_amdgcn_mfma_f32_16x16x32_bf16(qf0, tw0, a, 0, 0, 0);
    a = __builtin_amdgcn_mfma_f32_16x16x32_bf16(qf1, tw1, a, 0, 0, 0);
#pragma unroll
    for (int r = 0; r < 4; ++r)
      rwt[(lg * 4 + r) * 68 + jt * 16 + lr] = __float2bfloat16(a[r] * L2E);
  }
  float rwreg[8];
#pragma unroll
  for (int i = 0; i < 8; ++i) {
    int k = (i >> 2) * 16 + lg * 4 + (i & 3);
    rwreg[i] = __bfloat162float(rwt[lr * 68 + (wq_lane - k + 31)]);
  }
  __syncthreads();   // all rw reads done before DMA overwrites K/V region; drains vmem

  f32x4 O[4] = {};
  float m_ = -1e30f, lsum = 0.f;
  const float C = 0.125f * L2E;
  char* pc = lds + 32768 + w * 2048;       // P tile: [16 rows][8 slots x 16B] swizzled
  char* vcb = lds + 16384;                 // V single buffer

  int g_ = lane >> 3;                      // row-in-8
  int colb = ((lane & 7) ^ g_) * 8;        // pre-swizzled source col

  // ---- prologue: stage chunk-0 K into buf 0 (1 op/wave, left in flight) ----
  gload16(&Kb[(size_t)(w * 8 + g_) * 64 + colb], lds + w * 1024);

  int cur = 0;
#pragma unroll 1
  for (int kv0 = 0; kv0 < 1024; kv0 += 64) {
    __builtin_amdgcn_sched_barrier(0);
    __builtin_amdgcn_s_barrier();          // A: PV(prev) done; K[cur^1] reads done
    gload16(&Vb[(size_t)(w * 8 + g_) * 1024 + kv0 + colb], vcb + w * 1024);
    int nkv = (kv0 + 64 < 1024) ? kv0 + 64 : 960;  // last iter: dummy restage
    gload16(&Kb[(size_t)(nkv + w * 8 + g_) * 64 + colb], lds + (cur ^ 1) * 8192 + w * 1024);
    asm volatile("s_waitcnt vmcnt(2)" ::: "memory");
    __builtin_amdgcn_sched_barrier(0);
    __builtin_amdgcn_s_barrier();          // B: ALL waves' K_cur retired
    __builtin_amdgcn_sched_barrier(0);

    const char* kc = lds + cur * 8192;
    short8 kf[8];
#pragma unroll
    for (int t = 0; t < 4; ++t)
#pragma unroll
      for (int h = 0; h < 2; ++h)
        kf[2 * t + h] = *(const short8*)(kc + (t * 16 + lr) * 128 + (((h * 4 + lg) ^ xr) * 16));
    f32x4 st[4];
    __builtin_amdgcn_s_setprio(1);
#pragma unroll
    for (int t = 0; t < 4; ++t) {
      f32x4 z = {};
      z = __builtin_amdgcn_mfma_f32_16x16x32_bf16(kf[2 * t], qf0, z, 0, 0, 0);
      z = __builtin_amdgcn_mfma_f32_16x16x32_bf16(kf[2 * t + 1], qf1, z, 0, 0, 0);
      st[t] = z;
    }
    __builtin_amdgcn_s_setprio(0);
    int s_ = kv0 >> 6;
    unsigned bu = *(const unsigned*)(rhb + lr * 64 + ((s_ ^ lr) << 2));
    float bh0 = __uint_as_float(bu << 16);
    float bh1 = __uint_as_float(bu & 0xffff0000u);
    float mx = -1e30f;
#pragma unroll
    for (int t = 0; t < 4; ++t)
#pragma unroll
      for (int r = 0; r < 4; ++r) {
        float sv = fmaf(st[t][r], C, ((t < 2) ? bh0 : bh1) + rwreg[(t & 1) * 4 + r]);
        st[t][r] = sv;
        mx = fmaxf(mx, sv);
      }
    if (!__all(mx <= m_ + 8.f)) {
      float mw = fmaxf(mx, __shfl_xor(mx, 16, 64));
      mw = fmaxf(mw, __shfl_xor(mw, 32, 64));
      float mnew = fmaxf(m_, mw);
      float al = exp2f(m_ - mnew);
      lsum *= al;
      m_ = mnew;
#pragma unroll
      for (int r = 0; r < 4; ++r) {
        float av = __shfl(al, lg * 4 + r, 64);
#pragma unroll
        for (int dt = 0; dt < 4; ++dt) O[dt][r] *= av;
      }
    }
    float sa = 0.f;
#pragma unroll
    for (int t = 0; t < 4; ++t) {
      float p0 = exp2f(st[t][0] - m_);
      float p1 = exp2f(st[t][1] - m_);
      float p2 = exp2f(st[t][2] - m_);
      float p3 = exp2f(st[t][3] - m_);
      sa += (p0 + p1) + (p2 + p3);
      uint2 wv;
      wv.x = packtrunc(p0, p1);
      wv.y = packtrunc(p2, p3);
      int slot = (2 * t + (lg >> 1)) ^ xr;
      *(uint2*)(pc + lr * 128 + slot * 16 + (lg & 1) * 8) = wv;
    }
    lsum += sa;
    short8 pf0 = *(const short8*)(pc + lr * 128 + (((0 + lg) ^ xr) * 16));
    short8 pf1 = *(const short8*)(pc + lr * 128 + (((4 + lg) ^ xr) * 16));
    asm volatile("s_waitcnt vmcnt(1)" ::: "memory");
    __builtin_amdgcn_sched_barrier(0);
    __builtin_amdgcn_s_barrier();          // C: ALL waves' V_cur retired
    __builtin_amdgcn_sched_barrier(0);
    __builtin_amdgcn_s_setprio(1);
#pragma unroll
    for (int dt = 0; dt < 4; ++dt) {
      short8 vf0 = *(const short8*)(vcb + (dt * 16 + lr) * 128 + (((0 + lg) ^ xr) * 16));
      short8 vf1 = *(const short8*)(vcb + (dt * 16 + lr) * 128 + (((4 + lg) ^ xr) * 16));
      O[dt] = __builtin_amdgcn_mfma_f32_16x16x32_bf16(pf0, vf0, O[dt], 0, 0, 0);
      O[dt] = __builtin_amdgcn_mfma_f32_16x16x32_bf16(pf1, vf1, O[dt], 0, 0, 0);
    }
    __builtin_amdgcn_s_setprio(0);
    cur ^= 1;
  }

  float lt = lsum;
  lt += __shfl_xor(lt, 16, 64);
  lt += __shfl_xor(lt, 32, 64);
  float linv = 1.f / lt;
#pragma unroll
  for (int r = 0; r < 4; ++r) {
    float lv = __shfl(linv, lg * 4 + r, 64);
    int n = q0 + lg * 4 + r;
#pragma unroll
    for (int dt = 0; dt < 4; ++dt) {
      int d = dt * 16 + lr;
      int Sidx = bh * 65536 + n * 64 + d;
      int b = Sidx / 786432, r1 = Sidx % 786432;
      int pp = r1 / 24576, r2 = r1 % 24576;
      int qq = r2 / 768, r3 = r2 % 768;
      int j = r3 >> 6, dd = r3 & 63;
      int P = b * 786432 + j * 65536 + pp * 2048 + qq * 64 + dd;
      outp[P] = __float2bfloat16(O[dt][r] * lv);
    }
  }
}

extern "C" void kernel_launch(void* const* d_in, const int* in_sizes, int n_in,
                              void* d_out, int out_size, void* d_ws, size_t ws_size,
                              hipStream_t stream) {
  const float* x     = (const float*)d_in[0];
  const float* Wqkv  = (const float*)d_in[1];
  const float* bqkv  = (const float*)d_in[2];
  const float* Wproj = (const float*)d_in[3];
  const float* bproj = (const float*)d_in[4];
  const float* rph   = (const float*)d_in[5];
  const float* rpw   = (const float*)d_in[6];
  float* out = (float*)d_out;
  char* ws = (char*)d_ws;

  __hip_bfloat16* xb     = (__hip_bfloat16*)(ws);
  __hip_bfloat16* wqkvT  = (__hip_bfloat16*)(ws + 12582912);
  __hip_bfloat16* wprojT = (__hip_bfloat16*)(ws + 16121856);
  __hip_bfloat16* qkvb   = (__hip_bfloat16*)(ws + 17301504);  // Vrow, then attn-out
  __hip_bfloat16* Qm     = (__hip_bfloat16*)(ws + 55050240);
  __hip_bfloat16* Km     = (__hip_bfloat16*)(ws + 67633152);
  __hip_bfloat16* Vtm    = (__hip_bfloat16*)(ws + 80216064);
  __hip_bfloat16* Vrow   = qkvb;   // 12.6MB, dead before attn writes its output

  cast_f32_bf16<<<dim3(6144), dim3(256), 0, stream>>>(x, xb);
  transpose_cast_pi<<<dim3(72, 24), dim3(256), 0, stream>>>(Wqkv, wqkvT);
  transpose_cast<<<dim3(24, 24), dim3(256), 0, stream>>>(Wproj, wprojT, 768, 768);
  gemm_pipe<128, 1><<<dim3(18, 64), dim3(256), 0, stream>>>(
      xb, wqkvT, bqkv, nullptr, Qm, Km, Vrow, 2304, 768);
  vtrans<<<dim3(16, 96), dim3(256), 0, stream>>>(Vrow, Vtm);
  attn14<<<dim3(768), dim3(512), 0, stream>>>(Qm, Km, Vtm, rph, rpw, qkvb);
  gemm_pipe<64, 0><<<dim3(6, 128), dim3(256), 0, stream>>>(
      qkvb, wprojT, bproj, out, nullptr, nullptr, nullptr, 768, 768);
}

// Round 22
// 146.032 us; speedup vs baseline: 1.0279x; 1.0279x over previous
//
#include <hip/hip_runtime.h>
#include <hip/hip_bf16.h>

// Shapes (fixed): B=8, H=W=32, E=768, nh=12, hd=64, N=1024, BH=96
// ws layout (bytes):
//   xb      @ 0          : 12,582,912  (x cast to bf16)
//   wqkvT   @ 12582912   :  3,538,944  (Wqkv^T bf16, PI-column-ordered)
//   wprojT  @ 16121856   :  1,179,648  (Wproj^T bf16)
//   qkvb    @ 17301504   : 37,748,736  (Vrow bf16 [12.6MB], then attn-out bf16)
//   Q       @ 55050240   : 12,582,912
//   K       @ 67633152   : 12,582,912
//   Vt      @ 80216064   : 12,582,912  (V transposed: [bh][d][n])

typedef __attribute__((ext_vector_type(8))) short short8;
typedef __attribute__((ext_vector_type(4))) float f32x4;

// Fused prep: blocks [0,6144) cast x->bf16; [6144,7872) PI-transpose Wqkv;
// [7872,8448) plain transpose Wproj. (3 prep launches -> 1: kills 2 gaps.)
__global__ __launch_bounds__(256) void prep(const float* __restrict__ x,
                                            __hip_bfloat16* __restrict__ xb,
                                            const float* __restrict__ Wqkv,
                                            __hip_bfloat16* __restrict__ wqkvT,
                                            const float* __restrict__ Wproj,
                                            __hip_bfloat16* __restrict__ wprojT) {
  __shared__ float tile[32][33];
  int b = blockIdx.x;
  int tid = threadIdx.x;
  if (b < 6144) {
    int i = (b * 256 + tid) * 4;
    float4 v = *(const float4*)&x[i];
    xb[i + 0] = __float2bfloat16(v.x);
    xb[i + 1] = __float2bfloat16(v.y);
    xb[i + 2] = __float2bfloat16(v.z);
    xb[i + 3] = __float2bfloat16(v.w);
  } else if (b < 6144 + 1728) {
    // PI-ordered transpose for Wqkv (verified R18): column j = c2*768+h*64+d2
    // (dest coords), source pi(j) = h*192 + (u&63)*3 + (u>>6), u = 3*d2+c2.
    int t = b - 6144;
    int n0 = (t % 72) * 32, k0 = (t / 72) * 32;
    int tx = tid & 31, ty = tid >> 5;
    int j = n0 + tx;
    int c2 = j / 768, rem = j - c2 * 768;
    int h = rem >> 6, d2 = rem & 63;
    int u = 3 * d2 + c2;
    int src = h * 192 + (u & 63) * 3 + (u >> 6);
#pragma unroll
    for (int i = 0; i < 4; ++i)
      tile[ty + i * 8][tx] = Wqkv[(size_t)(k0 + ty + i * 8) * 2304 + src];
    __syncthreads();
#pragma unroll
    for (int i = 0; i < 4; ++i)
      wqkvT[(size_t)(n0 + ty + i * 8) * 768 + k0 + tx] =
          __float2bfloat16(tile[tx][ty + i * 8]);
  } else {
    int t = b - 6144 - 1728;
    int n0 = (t % 24) * 32, k0 = (t / 24) * 32;
    int tx = tid & 31, ty = tid >> 5;
#pragma unroll
    for (int i = 0; i < 4; ++i)
      tile[ty + i * 8][tx] = Wproj[(size_t)(k0 + ty + i * 8) * 768 + n0 + tx];
    __syncthreads();
#pragma unroll
    for (int i = 0; i < 4; ++i)
      wprojT[(size_t)(n0 + ty + i * 8) * 768 + k0 + tx] =
          __float2bfloat16(tile[tx][ty + i * 8]);
  }
}

// Vrow [bh][n][d] -> Vt [bh][d][n], LDS-tiled 64x64.
__global__ __launch_bounds__(256) void vtrans(const __hip_bfloat16* __restrict__ Vrow,
                                              __hip_bfloat16* __restrict__ Vt) {
  int bh = blockIdx.y, n0 = blockIdx.x * 64;
  __shared__ short t[64][72];
  int tid = threadIdx.x;
  const short* src = (const short*)Vrow + (size_t)bh * 65536 + (size_t)n0 * 64;
#pragma unroll
  for (int i = 0; i < 2; ++i) {
    int c8 = tid + i * 256;          // 0..511 chunks of 8
    int nl = c8 >> 3, off = (c8 & 7) * 8;
    *(short8*)&t[nl][off] = *(const short8*)&src[nl * 64 + off];
  }
  __syncthreads();
  int d = tid >> 2, g4 = tid & 3;
  short8 v0, v1;
#pragma unroll
  for (int j = 0; j < 8; ++j) v0[j] = t[g4 * 16 + j][d];
#pragma unroll
  for (int j = 0; j < 8; ++j) v1[j] = t[g4 * 16 + 8 + j][d];
  size_t base = (size_t)bh * 65536 + (size_t)d * 1024 + n0 + g4 * 16;
  *(short8*)&Vt[base] = v0;
  *(short8*)&Vt[base + 8] = v1;
}

__device__ inline void gload16(const void* g, void* l) {
  __builtin_amdgcn_global_load_lds((const __attribute__((address_space(1))) void*)g,
                                   (__attribute__((address_space(3))) void*)l, 16, 0, 0);
}

// C = A[M,K]*Bt[N,K]^T + bias ; BMx128 tile, 4 waves (2x2), BK=64.
// Counted-vmcnt double-buffered pipeline + both-sides XOR swizzle (R16)
// + T5 setprio (neutral, kept).  MODE 0: f32 C (gemm2).
// MODE 1: PI-direct epilogue (gemm1), verified R19.
template<int BM, int MODE>
__global__ __launch_bounds__(256) void gemm_pipe(const __hip_bfloat16* __restrict__ A,
                                                 const __hip_bfloat16* __restrict__ Bt,
                                                 const float* __restrict__ bias,
                                                 float* __restrict__ Cf32,
                                                 __hip_bfloat16* __restrict__ Qd,
                                                 __hip_bfloat16* __restrict__ Kdd,
                                                 __hip_bfloat16* __restrict__ Vd,
                                                 int N, int K) {
  constexpr int FM = BM / 32;               // m-frags per wave (4 or 2)
  constexpr int ABYTES = BM * 128;          // bytes per A k-tile
  constexpr int AOPW = BM / 32;             // A DMA ops per wave per tile
  __shared__ __align__(16) char lds[2 * ABYTES + 2 * 16384];
  char* Abuf = lds;                         // [2][ABYTES]
  char* Bbuf = lds + 2 * ABYTES;            // [2][16384]
  int n0 = blockIdx.x * 128, m0 = blockIdx.y * BM;
  int tid = threadIdx.x, lane = tid & 63, wid = tid >> 6;
  int wm = wid >> 1, wn = wid & 1;
  int lr = lane & 15, lg = lane >> 4;
  int xr = lr & 7;
  int g_ = lane >> 3;                       // row-in-op (8 rows x 128B per op)
  int colsw = ((lane & 7) ^ g_) * 8;        // pre-swizzled source col (elements)
  f32x4 acc[FM][4] = {};

  // ---- prologue: stage k-tile 0 into buf 0 (AOPW+4 ops/wave, in flight) ----
#pragma unroll
  for (int j = 0; j < AOPW; ++j) {
    int op = wid * AOPW + j;
    gload16(&A[(size_t)(m0 + op * 8 + g_) * K + colsw], Abuf + op * 1024);
  }
#pragma unroll
  for (int j = 0; j < 4; ++j) {
    int op = wid * 4 + j;
    gload16(&Bt[(size_t)(n0 + op * 8 + g_) * K + colsw], Bbuf + op * 1024);
  }

  int cur = 0;
#pragma unroll 1
  for (int k0 = 0; k0 < K; k0 += 64) {
    __builtin_amdgcn_sched_barrier(0);
    __builtin_amdgcn_s_barrier();          // buf^1 reads (tile k-1) complete
    int kn = (k0 + 64 < K) ? k0 + 64 : k0; // last iter: dummy restage
#pragma unroll
    for (int j = 0; j < AOPW; ++j) {
      int op = wid * AOPW + j;
      gload16(&A[(size_t)(m0 + op * 8 + g_) * K + kn + colsw],
              Abuf + (cur ^ 1) * ABYTES + op * 1024);
    }
#pragma unroll
    for (int j = 0; j < 4; ++j) {
      int op = wid * 4 + j;
      gload16(&Bt[(size_t)(n0 + op * 8 + g_) * K + kn + colsw],
              Bbuf + (cur ^ 1) * 16384 + op * 1024);
    }
    // retire this wave's tile-k DMA (keep the AOPW+4 newest in flight)
    if constexpr (BM == 128) asm volatile("s_waitcnt vmcnt(8)" ::: "memory");
    else                     asm volatile("s_waitcnt vmcnt(6)" ::: "memory");
    __builtin_amdgcn_sched_barrier(0);
    __builtin_amdgcn_s_barrier();          // ALL waves' tile-k DMA retired
    __builtin_amdgcn_sched_barrier(0);

    const char* Ac = Abuf + cur * ABYTES;
    const char* Bc = Bbuf + cur * 16384;
#pragma unroll
    for (int ks = 0; ks < 2; ++ks) {
      short8 af[FM], bfr[4];
#pragma unroll
      for (int m = 0; m < FM; ++m) {
        int row = wm * (BM / 2) + m * 16 + lr;
        af[m] = *(const short8*)(Ac + row * 128 + (((ks * 4 + lg) ^ xr) * 16));
      }
#pragma unroll
      for (int n = 0; n < 4; ++n) {
        int row = wn * 64 + n * 16 + lr;
        bfr[n] = *(const short8*)(Bc + row * 128 + (((ks * 4 + lg) ^ xr) * 16));
      }
      __builtin_amdgcn_s_setprio(1);
#pragma unroll
      for (int m = 0; m < FM; ++m)
#pragma unroll
        for (int n = 0; n < 4; ++n)
          acc[m][n] = __builtin_amdgcn_mfma_f32_16x16x32_bf16(af[m], bfr[n], acc[m][n], 0, 0, 0);
      __builtin_amdgcn_s_setprio(0);
    }
    cur ^= 1;
  }
#pragma unroll
  for (int n = 0; n < 4; ++n) {
    int j = n0 + wn * 64 + n * 16 + lr;    // PI-ordered (dest-coord) column
    if constexpr (MODE == 0) {
      float bv = bias[j];
#pragma unroll
      for (int m = 0; m < FM; ++m) {
        int rowb = m0 + wm * (BM / 2) + m * 16 + lg * 4;
#pragma unroll
        for (int r = 0; r < 4; ++r)
          Cf32[(size_t)(rowb + r) * N + j] = acc[m][n][r] + bv;
      }
    } else {
      int c = j / 768, rem = j - c * 768;  // c uniform per frag, h per frag
      int h = rem >> 6, dd = rem & 63;     // dd lane-consecutive
      int u = 3 * dd + c;
      float bv = bias[h * 192 + (u & 63) * 3 + (u >> 6)];  // bias[pi(j)]
      __hip_bfloat16* dst = (c == 0) ? Qd : ((c == 1) ? Kdd : Vd);
#pragma unroll
      for (int m = 0; m < FM; ++m) {
        int rowb = m0 + wm * (BM / 2) + m * 16 + lg * 4;
#pragma unroll
        for (int r = 0; r < 4; ++r) {
          float v = acc[m][n][r] + bv;
          int W = (rowb + r) * 12 + h;
          int bh = W >> 10, n2 = W & 1023;
          dst[(size_t)bh * 65536 + n2 * 64 + dd] = __float2bfloat16(v);
        }
      }
    }
  }
}

__device__ inline short8 cvt8(const float* p) {
  short8 r;
#pragma unroll
  for (int j = 0; j < 8; ++j) {
    __hip_bfloat16 b = __float2bfloat16(p[j]);
    r[j] = *reinterpret_cast<const short*>(&b);
  }
  return r;
}

// truncation pack: [b_hi16 | a_hi16] in one v_perm_b32 (valid: P>=0, no NaN).
__device__ inline unsigned packtrunc(float a, float b) {
  return __builtin_amdgcn_perm(__float_as_uint(b), __float_as_uint(a), 0x07060302u);
}

// Flash attention v15 (= v14 + parallel max tree): 8 waves/block (512 thr),
// 16 q-rows/wave, grid 768. Counted-vmcnt protocol; LDS 49152 B.
#define L2E 1.44269504088896f
__global__ __launch_bounds__(512) void attn15(const __hip_bfloat16* __restrict__ Q,
                                              const __hip_bfloat16* __restrict__ Kd,
                                              const __hip_bfloat16* __restrict__ Vt,
                                              const float* __restrict__ rph,
                                              const float* __restrict__ rpw,
                                              __hip_bfloat16* __restrict__ outp) {
  int orig = blockIdx.x;                   // 768 = 8 xcd * 96
  int xcd = orig & 7, loc = orig >> 3;     // 96 per xcd
  int bh = xcd * 12 + (loc % 12);
  int qt = loc / 12;                       // 0..7 (128-row q tile)
  int tid = threadIdx.x;
  int lane = tid & 63, w = tid >> 6;       // w in [0,8)
  int lr = lane & 15, lg = lane >> 4;
  int xr = lr & 7;

  __shared__ __align__(16) char lds[49152];

  const __hip_bfloat16* Qb = Q + (size_t)bh * 65536;
  const __hip_bfloat16* Kb = Kd + (size_t)bh * 65536;
  const __hip_bfloat16* Vb = Vt + (size_t)bh * 65536;

  int q0 = qt * 128 + w * 16;              // this wave's 16 q-rows
  int hq = q0 >> 5;                        // = qt*4 + (w>>1)
  int wq_lane = (q0 & 31) + lr;            // = (w&1)*16 + lr

  short8 qf0 = *(const short8*)&Qb[(size_t)(q0 + lr) * 64 + lg * 8];
  short8 qf1 = *(const short8*)&Qb[(size_t)(q0 + lr) * 64 + 32 + lg * 8];

  // ---- rel-pos bias via MFMA (pre-scaled by L2E); swizzled-slot store ----
  char* rhb = lds + 24576 + w * 1024;      // [16 q][64B], pair-slot swizzled
#pragma unroll
  for (int kt = 0; kt < 2; ++kt) {
    int row = hq - (kt * 16 + lr) + 31;    // 0..62
    const float* tp = rph + (size_t)row * 64 + lg * 8;
    short8 th0 = cvt8(tp), th1 = cvt8(tp + 32);
    f32x4 a = {};
    a = __builtin_amdgcn_mfma_f32_16x16x32_bf16(qf0, th0, a, 0, 0, 0);
    a = __builtin_amdgcn_mfma_f32_16x16x32_bf16(qf1, th1, a, 0, 0, 0);
#pragma unroll
    for (int r = 0; r < 4; ++r) {
      int q = lg * 4 + r;                  // 0..15
      int e = kt * 16 + lr;                // kh element 0..31
      int sw = ((e >> 1) ^ q) << 2;
      *(__hip_bfloat16*)(rhb + q * 64 + sw + (e & 1) * 2) = __float2bfloat16(a[r] * L2E);
    }
  }
  // rw staging in the (still dead) K/V region: wave w at byte w*2176, [16][68] bf16
  __hip_bfloat16* rwt = (__hip_bfloat16*)(lds + w * 2176);
#pragma unroll
  for (int jt = 0; jt < 4; ++jt) {
    const float* tp = rpw + (size_t)(jt * 16 + lr) * 64 + lg * 8;
    short8 tw0 = cvt8(tp), tw1 = cvt8(tp + 32);
    f32x4 a = {};
    a = __builtin_amdgcn_mfma_f32_16x16x32_bf16(qf0, tw0, a, 0, 0, 0);
    a = __builtin_amdgcn_mfma_f32_16x16x32_bf16(qf1, tw1, a, 0, 0, 0);
#pragma unroll
    for (int r = 0; r < 4; ++r)
      rwt[(lg * 4 + r) * 68 + jt * 16 + lr] = __float2bfloat16(a[r] * L2E);
  }
  float rwreg[8];
#pragma unroll
  for (int i = 0; i < 8; ++i) {
    int k = (i >> 2) * 16 + lg * 4 + (i & 3);
    rwreg[i] = __bfloat162float(rwt[lr * 68 + (wq_lane - k + 31)]);
  }
  __syncthreads();   // all rw reads done before DMA overwrites K/V region; drains vmem

  f32x4 O[4] = {};
  float m_ = -1e30f, lsum = 0.f;
  const float C = 0.125f * L2E;
  char* pc = lds + 32768 + w * 2048;       // P tile: [16 rows][8 slots x 16B] swizzled
  char* vcb = lds + 16384;                 // V single buffer

  int g_ = lane >> 3;                      // row-in-8
  int colb = ((lane & 7) ^ g_) * 8;        // pre-swizzled source col

  // ---- prologue: stage chunk-0 K into buf 0 (1 op/wave, left in flight) ----
  gload16(&Kb[(size_t)(w * 8 + g_) * 64 + colb], lds + w * 1024);

  int cur = 0;
#pragma unroll 1
  for (int kv0 = 0; kv0 < 1024; kv0 += 64) {
    __builtin_amdgcn_sched_barrier(0);
    __builtin_amdgcn_s_barrier();          // A: PV(prev) done; K[cur^1] reads done
    gload16(&Vb[(size_t)(w * 8 + g_) * 1024 + kv0 + colb], vcb + w * 1024);
    int nkv = (kv0 + 64 < 1024) ? kv0 + 64 : 960;  // last iter: dummy restage
    gload16(&Kb[(size_t)(nkv + w * 8 + g_) * 64 + colb], lds + (cur ^ 1) * 8192 + w * 1024);
    asm volatile("s_waitcnt vmcnt(2)" ::: "memory");
    __builtin_amdgcn_sched_barrier(0);
    __builtin_amdgcn_s_barrier();          // B: ALL waves' K_cur retired
    __builtin_amdgcn_sched_barrier(0);

    const char* kc = lds + cur * 8192;
    short8 kf[8];
#pragma unroll
    for (int t = 0; t < 4; ++t)
#pragma unroll
      for (int h = 0; h < 2; ++h)
        kf[2 * t + h] = *(const short8*)(kc + (t * 16 + lr) * 128 + (((h * 4 + lg) ^ xr) * 16));
    f32x4 st[4];
    __builtin_amdgcn_s_setprio(1);
#pragma unroll
    for (int t = 0; t < 4; ++t) {
      f32x4 z = {};
      z = __builtin_amdgcn_mfma_f32_16x16x32_bf16(kf[2 * t], qf0, z, 0, 0, 0);
      z = __builtin_amdgcn_mfma_f32_16x16x32_bf16(kf[2 * t + 1], qf1, z, 0, 0, 0);
      st[t] = z;
    }
    __builtin_amdgcn_s_setprio(0);
    int s_ = kv0 >> 6;
    unsigned bu = *(const unsigned*)(rhb + lr * 64 + ((s_ ^ lr) << 2));
    float bh0 = __uint_as_float(bu << 16);
    float bh1 = __uint_as_float(bu & 0xffff0000u);
#pragma unroll
    for (int t = 0; t < 4; ++t)
#pragma unroll
      for (int r = 0; r < 4; ++r)
        st[t][r] = fmaf(st[t][r], C, ((t < 2) ? bh0 : bh1) + rwreg[(t & 1) * 4 + r]);
    // parallel max tree (max3-fusable, short dep chain)
    float a0 = fmaxf(fmaxf(st[0][0], st[0][1]), fmaxf(st[0][2], st[0][3]));
    float a1 = fmaxf(fmaxf(st[1][0], st[1][1]), fmaxf(st[1][2], st[1][3]));
    float a2 = fmaxf(fmaxf(st[2][0], st[2][1]), fmaxf(st[2][2], st[2][3]));
    float a3 = fmaxf(fmaxf(st[3][0], st[3][1]), fmaxf(st[3][2], st[3][3]));
    float mx = fmaxf(fmaxf(a0, a1), fmaxf(a2, a3));
    if (!__all(mx <= m_ + 8.f)) {
      float mw = fmaxf(mx, __shfl_xor(mx, 16, 64));
      mw = fmaxf(mw, __shfl_xor(mw, 32, 64));
      float mnew = fmaxf(m_, mw);
      float al = exp2f(m_ - mnew);
      lsum *= al;
      m_ = mnew;
#pragma unroll
      for (int r = 0; r < 4; ++r) {
        float av = __shfl(al, lg * 4 + r, 64);
#pragma unroll
        for (int dt = 0; dt < 4; ++dt) O[dt][r] *= av;
      }
    }
    float sa = 0.f;
#pragma unroll
    for (int t = 0; t < 4; ++t) {
      float p0 = exp2f(st[t][0] - m_);
      float p1 = exp2f(st[t][1] - m_);
      float p2 = exp2f(st[t][2] - m_);
      float p3 = exp2f(st[t][3] - m_);
      sa += (p0 + p1) + (p2 + p3);
      uint2 wv;
      wv.x = packtrunc(p0, p1);
      wv.y = packtrunc(p2, p3);
      int slot = (2 * t + (lg >> 1)) ^ xr;
      *(uint2*)(pc + lr * 128 + slot * 16 + (lg & 1) * 8) = wv;
    }
    lsum += sa;
    short8 pf0 = *(const short8*)(pc + lr * 128 + (((0 + lg) ^ xr) * 16));
    short8 pf1 = *(const short8*)(pc + lr * 128 + (((4 + lg) ^ xr) * 16));
    asm volatile("s_waitcnt vmcnt(1)" ::: "memory");
    __builtin_amdgcn_sched_barrier(0);
    __builtin_amdgcn_s_barrier();          // C: ALL waves' V_cur retired
    __builtin_amdgcn_sched_barrier(0);
    __builtin_amdgcn_s_setprio(1);
#pragma unroll
    for (int dt = 0; dt < 4; ++dt) {
      short8 vf0 = *(const short8*)(vcb + (dt * 16 + lr) * 128 + (((0 + lg) ^ xr) * 16));
      short8 vf1 = *(const short8*)(vcb + (dt * 16 + lr) * 128 + (((4 + lg) ^ xr) * 16));
      O[dt] = __builtin_amdgcn_mfma_f32_16x16x32_bf16(pf0, vf0, O[dt], 0, 0, 0);
      O[dt] = __builtin_amdgcn_mfma_f32_16x16x32_bf16(pf1, vf1, O[dt], 0, 0, 0);
    }
    __builtin_amdgcn_s_setprio(0);
    cur ^= 1;
  }

  float lt = lsum;
  lt += __shfl_xor(lt, 16, 64);
  lt += __shfl_xor(lt, 32, 64);
  float linv = 1.f / lt;
#pragma unroll
  for (int r = 0; r < 4; ++r) {
    float lv = __shfl(linv, lg * 4 + r, 64);
    int n = q0 + lg * 4 + r;
#pragma unroll
    for (int dt = 0; dt < 4; ++dt) {
      int d = dt * 16 + lr;
      int Sidx = bh * 65536 + n * 64 + d;
      int b = Sidx / 786432, r1 = Sidx % 786432;
      int pp = r1 / 24576, r2 = r1 % 24576;
      int qq = r2 / 768, r3 = r2 % 768;
      int j = r3 >> 6, dd = r3 & 63;
      int P = b * 786432 + j * 65536 + pp * 2048 + qq * 64 + dd;
      outp[P] = __float2bfloat16(O[dt][r] * lv);
    }
  }
}

extern "C" void kernel_launch(void* const* d_in, const int* in_sizes, int n_in,
                              void* d_out, int out_size, void* d_ws, size_t ws_size,
                              hipStream_t stream) {
  const float* x     = (const float*)d_in[0];
  const float* Wqkv  = (const float*)d_in[1];
  const float* bqkv  = (const float*)d_in[2];
  const float* Wproj = (const float*)d_in[3];
  const float* bproj = (const float*)d_in[4];
  const float* rph   = (const float*)d_in[5];
  const float* rpw   = (const float*)d_in[6];
  float* out = (float*)d_out;
  char* ws = (char*)d_ws;

  __hip_bfloat16* xb     = (__hip_bfloat16*)(ws);
  __hip_bfloat16* wqkvT  = (__hip_bfloat16*)(ws + 12582912);
  __hip_bfloat16* wprojT = (__hip_bfloat16*)(ws + 16121856);
  __hip_bfloat16* qkvb   = (__hip_bfloat16*)(ws + 17301504);  // Vrow, then attn-out
  __hip_bfloat16* Qm     = (__hip_bfloat16*)(ws + 55050240);
  __hip_bfloat16* Km     = (__hip_bfloat16*)(ws + 67633152);
  __hip_bfloat16* Vtm    = (__hip_bfloat16*)(ws + 80216064);
  __hip_bfloat16* Vrow   = qkvb;   // 12.6MB, dead before attn writes its output

  prep<<<dim3(8448), dim3(256), 0, stream>>>(x, xb, Wqkv, wqkvT, Wproj, wprojT);
  gemm_pipe<128, 1><<<dim3(18, 64), dim3(256), 0, stream>>>(
      xb, wqkvT, bqkv, nullptr, Qm, Km, Vrow, 2304, 768);
  vtrans<<<dim3(16, 96), dim3(256), 0, stream>>>(Vrow, Vtm);
  attn15<<<dim3(768), dim3(512), 0, stream>>>(Qm, Km, Vtm, rph, rpw, qkvb);
  gemm_pipe<64, 0><<<dim3(6, 128), dim3(256), 0, stream>>>(
      qkvb, wprojT, bproj, out, nullptr, nullptr, nullptr, 768, 768);
}